// Round 1
// baseline (1129.047 us; speedup 1.0000x reference)
//
#include <hip/hip_runtime.h>
#include <hip/hip_bf16.h>

#define Bb   16
#define Nn   10000
#define Cc   256
#define Hh   4
#define KDk  16
#define Ee   320000
#define Mm   (Bb * Nn)   // 160000

__device__ __forceinline__ float elu1f(float x) {
  return x > 0.f ? x + 1.f : __expf(x);
}

// ---------------- CSR build ----------------
__global__ __launch_bounds__(256) void count_k(const int* __restrict__ rows,
                                               int* __restrict__ counts) {
  int e = blockIdx.x * 256 + threadIdx.x;
  if (e < Ee) atomicAdd(&counts[rows[e]], 1);
}

// single block, 1024 threads; counts[Nn] -> exclusive prefix rp[Nn+1]
__global__ __launch_bounds__(1024) void scan_k(const int* __restrict__ counts,
                                               int* __restrict__ rp) {
  __shared__ int sums[1024];
  const int t = threadIdx.x;
  const int base = t * 10;
  int local[10];
  int run = 0;
#pragma unroll
  for (int i = 0; i < 10; ++i) {
    local[i] = run;
    int idx = base + i;
    run += (idx < Nn) ? counts[idx] : 0;
  }
  sums[t] = run;
  __syncthreads();
  for (int off = 1; off < 1024; off <<= 1) {
    int v = (t >= off) ? sums[t - off] : 0;
    __syncthreads();
    sums[t] += v;
    __syncthreads();
  }
  int offset = (t > 0) ? sums[t - 1] : 0;
#pragma unroll
  for (int i = 0; i < 10; ++i) {
    int idx = base + i;
    if (idx <= Nn) rp[idx] = offset + local[i];
  }
}

__global__ __launch_bounds__(256) void fill_k(const int* __restrict__ rows,
                                              const int* __restrict__ cols,
                                              const float* __restrict__ vals,
                                              const int* __restrict__ rp,
                                              int* __restrict__ cur,
                                              int* __restrict__ colsS,
                                              float* __restrict__ valsS) {
  int e = blockIdx.x * 256 + threadIdx.x;
  if (e >= Ee) return;
  int r = rows[e];
  int p = atomicAdd(&cur[r], 1);
  int s = rp[r] + p;
  colsS[s] = cols[e];
  valsS[s] = vals[e];
}

// ---------------- fused QKV GEMM ----------------
// grid (6, 2500), block 256. cb 0: k (elu+1 -> kt [N, B*64]); cb 1: q (elu+1 ->
// qb [M,64]); cb 2..5: v (raw, scattered directly into d_out final layout).
__global__ __launch_bounds__(256) void qkv_gemm(
    const float* __restrict__ x, const float* __restrict__ Wk,
    const float* __restrict__ Wq, const float* __restrict__ Wv,
    float* __restrict__ kt, float* __restrict__ qb, float* __restrict__ out) {
  __shared__ float xs[32][68];  // [k][row], +4 pad
  __shared__ float ws[32][68];  // [k][col], +4 pad
  const int t = threadIdx.x;
  const int cb = blockIdx.x;
  const int m0 = blockIdx.y * 64;
  const float* W;
  int ldw, colbase;
  if (cb == 0) {
    W = Wk; ldw = 64; colbase = 0;
  } else if (cb == 1) {
    W = Wq; ldw = 64; colbase = 0;
  } else {
    W = Wv; ldw = 256; colbase = (cb - 2) * 64;
  }
  float acc[4][4] = {{0.f, 0.f, 0.f, 0.f}};
  const int tr = t & 15, tc = t >> 4;
  const int xr = t >> 3, xk = (t & 7) * 4;
  const int wkr = t >> 4, wc = (t & 15) * 4;

  for (int k0 = 0; k0 < 256; k0 += 32) {
    __syncthreads();
    float4 a0 = *(const float4*)(x + (size_t)(m0 + xr) * 256 + k0 + xk);
    float4 a1 = *(const float4*)(x + (size_t)(m0 + xr + 32) * 256 + k0 + xk);
    float4 w0 = *(const float4*)(W + (size_t)(k0 + wkr) * ldw + colbase + wc);
    float4 w1 = *(const float4*)(W + (size_t)(k0 + wkr + 16) * ldw + colbase + wc);
    xs[xk + 0][xr] = a0.x; xs[xk + 1][xr] = a0.y;
    xs[xk + 2][xr] = a0.z; xs[xk + 3][xr] = a0.w;
    xs[xk + 0][xr + 32] = a1.x; xs[xk + 1][xr + 32] = a1.y;
    xs[xk + 2][xr + 32] = a1.z; xs[xk + 3][xr + 32] = a1.w;
    *(float4*)&ws[wkr][wc] = w0;
    *(float4*)&ws[wkr + 16][wc] = w1;
    __syncthreads();
#pragma unroll
    for (int kk = 0; kk < 32; ++kk) {
      float4 av = *(const float4*)&xs[kk][tr * 4];
      float4 bv = *(const float4*)&ws[kk][tc * 4];
      float a4[4] = {av.x, av.y, av.z, av.w};
      float b4[4] = {bv.x, bv.y, bv.z, bv.w};
#pragma unroll
      for (int i = 0; i < 4; ++i)
#pragma unroll
        for (int j = 0; j < 4; ++j) acc[i][j] = fmaf(a4[i], b4[j], acc[i][j]);
    }
  }

#pragma unroll
  for (int i = 0; i < 4; ++i) {
    int m = m0 + tr * 4 + i;
    int b = m / Nn;
    int n = m - b * Nn;
    float4 o = make_float4(acc[i][0], acc[i][1], acc[i][2], acc[i][3]);
    if (cb == 0) {
      o.x = elu1f(o.x); o.y = elu1f(o.y); o.z = elu1f(o.z); o.w = elu1f(o.w);
      *(float4*)(kt + (size_t)n * 1024 + b * 64 + tc * 4) = o;
    } else if (cb == 1) {
      o.x = elu1f(o.x); o.y = elu1f(o.y); o.z = elu1f(o.z); o.w = elu1f(o.w);
      *(float4*)(qb + (size_t)m * 64 + tc * 4) = o;
    } else {
      size_t obase = (size_t)(n & 15) * 2560000u +
                     (size_t)(b * 625 + (n >> 4)) * 256u + colbase + tc * 4;
      *(float4*)(out + obase) = o;
    }
  }
}

// ---------------- SpMM (CSR row per block) ----------------
// MODE 0: out[r] = d(col) * sum_e val*in[c]          (it1 = d .* (A@kt))
// MODE 1: out[r] += in[r] + d(col) * sum_e val*in[c] (kt += it1 + d .* (A@it1))
template <int MODE>
__global__ __launch_bounds__(256) void spmm_k(const float* __restrict__ in,
                                              float* __restrict__ out,
                                              const int* __restrict__ rp,
                                              const int* __restrict__ colsS,
                                              const float* __restrict__ valsS) {
  const int r = blockIdx.x;
  const int t = threadIdx.x;
  const int s = rp[r], e = rp[r + 1];
  float4 acc = make_float4(0.f, 0.f, 0.f, 0.f);
  for (int i = s; i < e; ++i) {
    const int c = colsS[i];
    const float v = valsS[i];
    const float4 xv = *(const float4*)(in + (size_t)c * 1024 + t * 4);
    acc.x = fmaf(v, xv.x, acc.x);
    acc.y = fmaf(v, xv.y, acc.y);
    acc.z = fmaf(v, xv.z, acc.z);
    acc.w = fmaf(v, xv.w, acc.w);
  }
  const float dh = 0.1f + (0.4f / 3.f) * ((t >> 2) & 3);  // h = (4t/16)%4
  const size_t o = (size_t)r * 1024 + t * 4;
  if (MODE == 0) {
    *(float4*)(out + o) = make_float4(dh * acc.x, dh * acc.y, dh * acc.z, dh * acc.w);
  } else {
    float4 c0 = *(const float4*)(out + o);
    float4 i1 = *(const float4*)(in + o);
    *(float4*)(out + o) =
        make_float4(c0.x + i1.x + dh * acc.x, c0.y + i1.y + dh * acc.y,
                    c0.z + i1.z + dh * acc.z, c0.w + i1.w + dh * acc.w);
  }
}

// ---------------- finalize: w, scale v, LayerNorm, in-place on d_out ----------
// one 64-lane wave per (b,n); block = 4 waves; grid = Mm/4
__global__ __launch_bounds__(256) void finalize_k(const float* __restrict__ kt,
                                                  const float* __restrict__ qb,
                                                  const float* __restrict__ gamma,
                                                  const float* __restrict__ beta,
                                                  float* __restrict__ out) {
  const int gid = blockIdx.x * 256 + threadIdx.x;
  const int m = gid >> 6;
  const int lane = threadIdx.x & 63;
  const int b = m / Nn;
  const int n = m - b * Nn;
  // w per head: acc = kt (holds k+it1+it2), q; reduce over 16-lane (kd) group
  float a = kt[(size_t)n * 1024 + b * 64 + lane];
  float q = qb[(size_t)m * 64 + lane];
  float p = a * q;
  p += __shfl_xor(p, 1);
  p += __shfl_xor(p, 2);
  p += __shfl_xor(p, 4);
  p += __shfl_xor(p, 8);
  const float w = p * (1.f / 16.f);  // lanes [16h,16h+16) hold w of head h
  const size_t obase =
      (size_t)(n & 15) * 2560000u + (size_t)(b * 625 + (n >> 4)) * 256u;
  float4 v = *(const float4*)(out + obase + lane * 4);
  v.x *= w; v.y *= w; v.z *= w; v.w *= w;
  float s1 = v.x + v.y + v.z + v.w;
  float s2 = v.x * v.x + v.y * v.y + v.z * v.z + v.w * v.w;
  s1 += __shfl_xor(s1, 1); s2 += __shfl_xor(s2, 1);
  s1 += __shfl_xor(s1, 2); s2 += __shfl_xor(s2, 2);
  s1 += __shfl_xor(s1, 4); s2 += __shfl_xor(s2, 4);
  s1 += __shfl_xor(s1, 8); s2 += __shfl_xor(s2, 8);
  const float mu = s1 * (1.f / 64.f);
  const float var = s2 * (1.f / 64.f) - mu * mu;
  const float inv = rsqrtf(var + 1e-5f);
  const int d0 = (lane & 15) * 4;
  float4 g = *(const float4*)(gamma + d0);
  float4 be = *(const float4*)(beta + d0);
  float4 o;
  o.x = (v.x - mu) * inv * g.x + be.x;
  o.y = (v.y - mu) * inv * g.y + be.y;
  o.z = (v.z - mu) * inv * g.z + be.z;
  o.w = (v.w - mu) * inv * g.w + be.w;
  *(float4*)(out + obase + lane * 4) = o;
}

extern "C" void kernel_launch(void* const* d_in, const int* in_sizes, int n_in,
                              void* d_out, int out_size, void* d_ws, size_t ws_size,
                              hipStream_t stream) {
  const float* x = (const float*)d_in[0];
  const float* edge_vals = (const float*)d_in[1];
  const float* Wk = (const float*)d_in[2];
  const float* Wq = (const float*)d_in[3];
  const float* Wv = (const float*)d_in[4];
  const float* gamma = (const float*)d_in[5];
  const float* beta = (const float*)d_in[6];
  const int* erows = (const int*)d_in[7];
  const int* ecols = (const int*)d_in[8];
  float* out = (float*)d_out;

  // workspace layout (~126 MB)
  float* ws = (float*)d_ws;
  float* kt = ws;                              // N*1024
  float* it1 = kt + (size_t)Nn * 1024;         // N*1024
  float* qb = it1 + (size_t)Nn * 1024;         // M*64 (= N*1024)
  float* vals_s = qb + (size_t)Mm * 64;        // E
  int* counts = (int*)(vals_s + Ee);           // N
  int* cur = counts + Nn;                      // N
  int* rp = cur + Nn;                          // N+1
  int* cols_s = rp + Nn + 1;                   // E

  hipMemsetAsync(counts, 0, 2 * Nn * sizeof(int), stream);  // counts + cur
  count_k<<<(Ee + 255) / 256, 256, 0, stream>>>(erows, counts);
  scan_k<<<1, 1024, 0, stream>>>(counts, rp);
  fill_k<<<(Ee + 255) / 256, 256, 0, stream>>>(erows, ecols, edge_vals, rp, cur,
                                               cols_s, vals_s);
  qkv_gemm<<<dim3(6, 2500), 256, 0, stream>>>(x, Wk, Wq, Wv, kt, qb, out);
  spmm_k<0><<<Nn, 256, 0, stream>>>(kt, it1, rp, cols_s, vals_s);
  spmm_k<1><<<Nn, 256, 0, stream>>>(it1, kt, rp, cols_s, vals_s);
  finalize_k<<<Mm / 4, 256, 0, stream>>>(kt, qb, gamma, beta, out);
}

// Round 2
// 300.929 us; speedup vs baseline: 3.7519x; 3.7519x over previous
//
#include <hip/hip_runtime.h>

#define Mm 160000
#define Nn 10000

typedef __attribute__((ext_vector_type(8))) short short8;
typedef __attribute__((ext_vector_type(4))) short short4v;
typedef __attribute__((ext_vector_type(4))) float float4v;

__device__ __forceinline__ short f2bf(float f) {
  // round-to-nearest-even fp32 -> bf16 (inputs are finite, no NaN handling)
  unsigned u = __builtin_bit_cast(unsigned, f);
  u = (u + 0x7FFFu + ((u >> 16) & 1u)) >> 16;
  return (short)u;
}

// Wv [k=256][n=256] fp32 -> Wv_bt [n][k] bf16 (tiny, one-shot)
__global__ __launch_bounds__(256) void prep_k(const float* __restrict__ Wv,
                                              short* __restrict__ bt) {
  const int n = blockIdx.x, k = threadIdx.x;
  bt[n * 256 + k] = f2bf(Wv[k * 256 + n]);
}

// One block = 64 rows x 256 cols of v = x@Wv, K=256.
// Wave w (0..3) owns head w (cols 64w..64w+63) -> per-head LayerNorm entirely
// in-wave. Output scattered directly to final layout:
//   out[(n%16)*2560000 + (b*625 + n/16)*256 + col]
__global__ __launch_bounds__(256) void gemm_ln(const float* __restrict__ x,
                                               const short* __restrict__ bt,
                                               const float* __restrict__ gamma,
                                               const float* __restrict__ beta,
                                               float* __restrict__ out) {
  __shared__ short A[64][72];    // [row][k], +8 pad: stride 144B -> 2-way max
  __shared__ short Bt[256][72];  // [n][k]
  const int t = threadIdx.x;
  const int m0 = blockIdx.x * 64;
  const int w = t >> 6;   // wave = head
  const int l = t & 63;
  const int c16 = l & 15;
  const int q8 = (l >> 4) * 8;

  float4v acc[4][4];
#pragma unroll
  for (int i = 0; i < 4; ++i)
#pragma unroll
    for (int j = 0; j < 4; ++j) acc[i][j] = (float4v){0.f, 0.f, 0.f, 0.f};

  const int ar = t >> 4, ak = (t & 15) * 4;   // A staging: 16 lanes cover a row
  const int bn = t >> 3, bk = (t & 7) * 8;    // B staging: 8 lanes cover a row

  for (int k0 = 0; k0 < 256; k0 += 64) {
    __syncthreads();
    // stage A: 64 rows x 64 k, fp32 global -> bf16 LDS (x read exactly once)
#pragma unroll
    for (int j = 0; j < 4; ++j) {
      float4 a = *(const float4*)(x + (size_t)(m0 + ar + j * 16) * 256 + k0 + ak);
      short4v s;
      s.x = f2bf(a.x); s.y = f2bf(a.y); s.z = f2bf(a.z); s.w = f2bf(a.w);
      *(short4v*)&A[ar + j * 16][ak] = s;
    }
    // stage Bt: 256 n-rows x 64 k bf16 (L2-resident, 16B loads)
#pragma unroll
    for (int j = 0; j < 8; ++j) {
      int4 v = *(const int4*)(bt + (size_t)(bn + j * 32) * 256 + k0 + bk);
      *(int4*)&Bt[bn + j * 32][bk] = v;
    }
    __syncthreads();
#pragma unroll
    for (int c = 0; c < 2; ++c) {  // two K=32 chunks
      short8 af[4], bf[4];
#pragma unroll
      for (int i = 0; i < 4; ++i)
        af[i] = *(const short8*)&A[i * 16 + c16][c * 32 + q8];
#pragma unroll
      for (int j = 0; j < 4; ++j)
        bf[j] = *(const short8*)&Bt[w * 64 + j * 16 + c16][c * 32 + q8];
#pragma unroll
      for (int i = 0; i < 4; ++i)
#pragma unroll
        for (int j = 0; j < 4; ++j)
          acc[i][j] = __builtin_amdgcn_mfma_f32_16x16x32_bf16(af[i], bf[j],
                                                              acc[i][j], 0, 0, 0);
    }
  }

  // Epilogue: per-head LayerNorm + scatter.
  // C/D layout: col = l&15 (within 16-tile), row = (l>>4)*4 + reg.
  float g[4], be[4];
#pragma unroll
  for (int j = 0; j < 4; ++j) {
    g[j] = gamma[j * 16 + c16];
    be[j] = beta[j * 16 + c16];
  }
  const int q4 = (l >> 4) * 4;
#pragma unroll
  for (int i = 0; i < 4; ++i) {
#pragma unroll
    for (int reg = 0; reg < 4; ++reg) {
      float s1 = acc[i][0][reg] + acc[i][1][reg] + acc[i][2][reg] + acc[i][3][reg];
      float s2 = acc[i][0][reg] * acc[i][0][reg] + acc[i][1][reg] * acc[i][1][reg] +
                 acc[i][2][reg] * acc[i][2][reg] + acc[i][3][reg] * acc[i][3][reg];
      s1 += __shfl_xor(s1, 1); s2 += __shfl_xor(s2, 1);
      s1 += __shfl_xor(s1, 2); s2 += __shfl_xor(s2, 2);
      s1 += __shfl_xor(s1, 4); s2 += __shfl_xor(s2, 4);
      s1 += __shfl_xor(s1, 8); s2 += __shfl_xor(s2, 8);
      const float mu = s1 * (1.f / 64.f);
      const float var = s2 * (1.f / 64.f) - mu * mu;
      const float inv = rsqrtf(var + 1e-5f);
      const int m = m0 + i * 16 + q4 + reg;
      const int b = m / Nn;
      const int n = m - b * Nn;
      const size_t obase = (size_t)(n & 15) * 2560000u +
                           (size_t)(b * 625 + (n >> 4)) * 256u + w * 64 + c16;
#pragma unroll
      for (int j = 0; j < 4; ++j)
        out[obase + j * 16] = (acc[i][j][reg] - mu) * inv * g[j] + be[j];
    }
  }
}

extern "C" void kernel_launch(void* const* d_in, const int* in_sizes, int n_in,
                              void* d_out, int out_size, void* d_ws, size_t ws_size,
                              hipStream_t stream) {
  const float* x = (const float*)d_in[0];
  const float* Wv = (const float*)d_in[4];
  const float* gamma = (const float*)d_in[5];
  const float* beta = (const float*)d_in[6];
  float* out = (float*)d_out;
  short* wv_bt = (short*)d_ws;  // 256*256 bf16 = 128 KB

  prep_k<<<256, 256, 0, stream>>>(Wv, wv_bt);
  gemm_ln<<<Mm / 64, 256, 0, stream>>>(x, wv_bt, gamma, beta, out);
}